// Round 8
// baseline (232.353 us; speedup 1.0000x reference)
//
#include <hip/hip_runtime.h>
#include <stdint.h>

#define NB 4096
#define QLEN 1024
#define NL 64
#define KLEN 32
#define NS (QLEN - KLEN + 1)   // 993
#define ROWS 2                 // batch rows per block; grid = NB/ROWS

typedef __attribute__((ext_vector_type(8))) _Float16 half8;
typedef __attribute__((ext_vector_type(4))) float f32x4;

union fragh { uint32_t u[4]; half8 v; };

static __device__ __forceinline__ uint32_t pkh(float a, float b) {
    return __builtin_bit_cast(uint32_t, __builtin_amdgcn_cvt_pkrtz(a, b)); // v_cvt_pkrtz_f16_f32
}
static __device__ __forceinline__ float lo16f(uint32_t w) {
    return (float)__builtin_bit_cast(_Float16, (unsigned short)(w & 0xFFFFu));
}
static __device__ __forceinline__ float hi16f(uint32_t w) {
    return (float)__builtin_bit_cast(_Float16, (unsigned short)(w >> 16));
}

__global__ __launch_bounds__(256, 6) void shapelet_r8(
    const float* __restrict__ ts,        // [B, Q]
    const float* __restrict__ shapelets, // [L, K]
    const float* __restrict__ fc_w,      // [2, L]
    const float* __restrict__ fc_b,      // [2]
    float* __restrict__ out)             // [B, 2]
{
    // 19.3 KB total -> 8 blocks/CU fits LDS; 8 blocks x 4 waves = 32 waves/CU
    __shared__ __align__(16) uint32_t lds_pkE[ROWS][544]; // f16(x[2i]) | f16(x[2i+1])<<16
    __shared__ __align__(16) uint32_t lds_pkO[ROWS][544]; // f16(x[2i+1]) | f16(x[2i+2])<<16
    __shared__ __align__(16) float    lds_nwin[ROWS][QLEN]; // -0.5*win_sq; -1e30 masks s>=NS
    __shared__ __align__(16) float    lds_s4[ROWS][264];  // 4-square partials; reused as pm
    __shared__ float lds_ssq[NL];

    const int tid  = threadIdx.x;
    const int b0   = blockIdx.x * ROWS;
    const int lane = tid & 63;
    const int wave = tid >> 6;
    const int col  = lane & 15;
    const int kg   = lane >> 4;

    // --- pass 1 (both rows): global float4 -> f16 phase-packs + square partials ---
    #pragma unroll
    for (int r = 0; r < ROWS; ++r) {
        const float* row = ts + (size_t)(b0 + r) * QLEN;
        float4 v = reinterpret_cast<const float4*>(row)[tid];
        float x4g = (tid < 255) ? row[4 * tid + 4] : 0.0f;
        uint2 pe = { pkh(v.x, v.y), pkh(v.z, v.w) };
        uint2 po = { pkh(v.y, v.z), pkh(v.w, x4g) };
        reinterpret_cast<uint2*>(lds_pkE[r])[tid] = pe;
        reinterpret_cast<uint2*>(lds_pkO[r])[tid] = po;
        lds_s4[r][tid] = fmaf(v.x, v.x, fmaf(v.y, v.y, fmaf(v.z, v.z, v.w * v.w)));
    }
    if (tid < 32) {
        lds_pkE[0][512 + tid] = 0u; lds_pkO[0][512 + tid] = 0u;
        lds_pkE[1][512 + tid] = 0u; lds_pkO[1][512 + tid] = 0u;
    }
    if (tid < 8) { lds_s4[0][256 + tid] = 0.0f; lds_s4[1][256 + tid] = 0.0f; }

    // --- B fragments: fp16 RTZ, all 4 l-tiles (16 VGPR), shared by both rows ---
    fragh Bh[4];
    #pragma unroll
    for (int lt = 0; lt < 4; ++lt) {
        const float* sp = shapelets + (lt * 16 + col) * KLEN + kg * 8;
        float4 f0 = *reinterpret_cast<const float4*>(sp);
        float4 f1 = *reinterpret_cast<const float4*>(sp + 4);
        Bh[lt].u[0] = pkh(f0.x, f0.y);
        Bh[lt].u[1] = pkh(f0.z, f0.w);
        Bh[lt].u[2] = pkh(f1.x, f1.y);
        Bh[lt].u[3] = pkh(f1.z, f1.w);
    }

    // --- per-shapelet sum of squares (fp32) ---
    if (tid < NL) {
        const float* sp = shapelets + tid * KLEN;
        float s = 0.0f;
        #pragma unroll
        for (int k = 0; k < KLEN; ++k) s = fmaf(sp[k], sp[k], s);
        lds_ssq[tid] = s;
    }
    __syncthreads();

    // --- pass 2 (both rows): win_sq from partials + f16 sliding corrections ---
    #pragma unroll
    for (int r = 0; r < ROWS; ++r) {
        float s[8];
        #pragma unroll
        for (int j = 0; j < 8; ++j) s[j] = lds_s4[r][tid + j];
        float w0 = ((s[0] + s[1]) + (s[2] + s[3])) + ((s[4] + s[5]) + (s[6] + s[7]));
        uint32_t a0 = lds_pkE[r][2 * tid];
        uint32_t a1 = lds_pkE[r][2 * tid + 1];
        uint32_t c0 = lds_pkE[r][2 * (tid + 8)];
        uint32_t c1 = lds_pkE[r][2 * (tid + 8) + 1];
        float x0 = lo16f(a0), x1 = hi16f(a0), x2 = lo16f(a1);
        float x32 = lo16f(c0), x33 = hi16f(c0), x34 = lo16f(c1);
        float w1 = fmaf(x32, x32, fmaf(-x0, x0, w0));
        float w2 = fmaf(x33, x33, fmaf(-x1, x1, w1));
        float w3 = fmaf(x34, x34, fmaf(-x2, x2, w2));
        const int p0 = 4 * tid;
        float4 wv;
        wv.x = (p0 + 0 < NS) ? -0.5f * w0 : -1.0e30f;
        wv.y = (p0 + 1 < NS) ? -0.5f * w1 : -1.0e30f;
        wv.z = (p0 + 2 < NS) ? -0.5f * w2 : -1.0e30f;
        wv.w = (p0 + 3 < NS) ? -0.5f * w3 : -1.0e30f;
        reinterpret_cast<float4*>(lds_nwin[r])[tid] = wv;
    }
    __syncthreads();

    // --- main loops: per row, wave covers positions [256*wave, 256*wave+256) ---
    const int par = col & 1;
    const int abase = ((col - par) >> 1) + kg * 4;
    float* pm = &lds_s4[0][0];   // alias (s4 dead after pass2 barrier); 512 floats

    #pragma unroll
    for (int r = 0; r < ROWS; ++r) {
        const uint32_t* apk = (par ? lds_pkO[r] : lds_pkE[r]) + abase;
        float rmax[4][4];
        #pragma unroll
        for (int lt = 0; lt < 4; ++lt)
            #pragma unroll
            for (int e = 0; e < 4; ++e) rmax[lt][e] = -3.0e38f;

        #pragma unroll
        for (int t = 0; t < 8; ++t) {     // 8 straight-line pair-steps
            const int s0 = 256 * wave + 32 * t;
            const uint32_t* ap = apk + (s0 >> 1);
            fragh Aa, Ab;
            #pragma unroll
            for (int j = 0; j < 4; ++j) Aa.u[j] = ap[j];
            #pragma unroll
            for (int j = 0; j < 4; ++j) Ab.u[j] = ap[8 + j];
            const f32x4 ia = *reinterpret_cast<const f32x4*>(&lds_nwin[r][s0 + kg * 4]);
            const f32x4 ib = *reinterpret_cast<const f32x4*>(&lds_nwin[r][s0 + 16 + kg * 4]);

            #pragma unroll
            for (int lt = 0; lt < 4; ++lt) {
                f32x4 aa = __builtin_amdgcn_mfma_f32_16x16x32_f16(Aa.v, Bh[lt].v, ia, 0, 0, 0);
                f32x4 ab = __builtin_amdgcn_mfma_f32_16x16x32_f16(Ab.v, Bh[lt].v, ib, 0, 0, 0);
                #pragma unroll
                for (int e = 0; e < 4; ++e)
                    rmax[lt][e] = fmaxf(fmaxf(aa[e], ab[e]), rmax[lt][e]);  // v_max3_f32
            }
        }

        // reduce: within-lane, cross-kg (same col); stash per-wave partials
        #pragma unroll
        for (int lt = 0; lt < 4; ++lt) {
            float v = fmaxf(fmaxf(rmax[lt][0], rmax[lt][1]),
                            fmaxf(rmax[lt][2], rmax[lt][3]));
            v = fmaxf(v, __shfl_xor(v, 16, 64));
            v = fmaxf(v, __shfl_xor(v, 32, 64));
            if (kg == 0) pm[r * 256 + wave * 64 + lt * 16 + col] = v;
        }
    }
    __syncthreads();

    // --- epilogue: wave r handles row b0+r ---
    if (wave < ROWS) {
        const int r = wave;
        float m = fmaxf(fmaxf(pm[r * 256 + 0 * 64 + lane], pm[r * 256 + 1 * 64 + lane]),
                        fmaxf(pm[r * 256 + 2 * 64 + lane], pm[r * 256 + 3 * 64 + lane]));
        float f = (lds_ssq[lane] - 2.0f * m) * (1.0f / (float)KLEN);  // min dist

        float p0v = f * fc_w[lane];
        float p1v = f * fc_w[NL + lane];
        #pragma unroll
        for (int off = 32; off >= 1; off >>= 1) {
            p0v += __shfl_xor(p0v, off, 64);
            p1v += __shfl_xor(p1v, off, 64);
        }
        if (lane == 0) {
            out[(size_t)(b0 + r) * 2 + 0] = p0v + fc_b[0];
            out[(size_t)(b0 + r) * 2 + 1] = p1v + fc_b[1];
        }
    }
}

extern "C" void kernel_launch(void* const* d_in, const int* in_sizes, int n_in,
                              void* d_out, int out_size, void* d_ws, size_t ws_size,
                              hipStream_t stream) {
    const float* ts        = (const float*)d_in[0];
    const float* shapelets = (const float*)d_in[1];
    const float* fc_w      = (const float*)d_in[2];
    const float* fc_b      = (const float*)d_in[3];
    float* out = (float*)d_out;

    shapelet_r8<<<NB / ROWS, 256, 0, stream>>>(ts, shapelets, fc_w, fc_b, out);
}

// Round 9
// 29.621 us; speedup vs baseline: 7.8442x; 7.8442x over previous
//
#include <hip/hip_runtime.h>
#include <stdint.h>

#define NB 4096
#define QLEN 1024
#define NL 64
#define KLEN 32
#define NS (QLEN - KLEN + 1)   // 993
#define ROWS 2                 // batch rows per block; grid = NB/ROWS = 2048

typedef __attribute__((ext_vector_type(8))) _Float16 half8;
typedef __attribute__((ext_vector_type(4))) float f32x4;

union fragh { uint32_t u[4]; half8 v; };

static __device__ __forceinline__ uint32_t pkh(float a, float b) {
    return __builtin_bit_cast(uint32_t, __builtin_amdgcn_cvt_pkrtz(a, b)); // v_cvt_pkrtz_f16_f32
}
static __device__ __forceinline__ float lo16f(uint32_t w) {
    return (float)__builtin_bit_cast(_Float16, (unsigned short)(w & 0xFFFFu));
}
static __device__ __forceinline__ float hi16f(uint32_t w) {
    return (float)__builtin_bit_cast(_Float16, (unsigned short)(w >> 16));
}

__global__ __launch_bounds__(256, 8) void shapelet_r9(
    const float* __restrict__ ts,        // [B, Q]
    const float* __restrict__ shapelets, // [L, K]
    const float* __restrict__ fc_w,      // [2, L]
    const float* __restrict__ fc_b,      // [2]
    float* __restrict__ out)             // [B, 2]
{
    // 19.4 KB -> 8 blocks/CU (155.6/160 KB); 8 blocks x 4 waves = 32 waves/CU
    __shared__ __align__(16) uint32_t lds_pkE[ROWS][544]; // f16(x[2i]) | f16(x[2i+1])<<16
    __shared__ __align__(16) uint32_t lds_pkO[ROWS][544]; // f16(x[2i+1]) | f16(x[2i+2])<<16
    __shared__ __align__(16) float    lds_nwin[ROWS][QLEN]; // -0.5*win_sq; -1e30 masks s>=NS
    __shared__ __align__(16) float    lds_s4[ROWS][264];  // 4-square partials; reused as pm
    __shared__ float lds_ssq[NL];

    const int tid  = threadIdx.x;
    const int b0   = blockIdx.x * ROWS;
    const int lane = tid & 63;
    const int wave = tid >> 6;
    const int col  = lane & 15;
    const int kg   = lane >> 4;

    // --- pass 1 (both rows): global float4 -> f16 phase-packs + square partials ---
    #pragma unroll
    for (int r = 0; r < ROWS; ++r) {
        const float* row = ts + (size_t)(b0 + r) * QLEN;
        float4 v = reinterpret_cast<const float4*>(row)[tid];
        float x4g = (tid < 255) ? row[4 * tid + 4] : 0.0f;
        uint2 pe = { pkh(v.x, v.y), pkh(v.z, v.w) };
        uint2 po = { pkh(v.y, v.z), pkh(v.w, x4g) };
        reinterpret_cast<uint2*>(lds_pkE[r])[tid] = pe;
        reinterpret_cast<uint2*>(lds_pkO[r])[tid] = po;
        lds_s4[r][tid] = fmaf(v.x, v.x, fmaf(v.y, v.y, fmaf(v.z, v.z, v.w * v.w)));
    }
    if (tid < 32) {
        lds_pkE[0][512 + tid] = 0u; lds_pkO[0][512 + tid] = 0u;
        lds_pkE[1][512 + tid] = 0u; lds_pkO[1][512 + tid] = 0u;
    }
    if (tid < 8) { lds_s4[0][256 + tid] = 0.0f; lds_s4[1][256 + tid] = 0.0f; }

    // --- B fragments: fp16 RTZ, all 4 l-tiles (16 VGPR), shared by both rows ---
    fragh Bh[4];
    #pragma unroll
    for (int lt = 0; lt < 4; ++lt) {
        const float* sp = shapelets + (lt * 16 + col) * KLEN + kg * 8;
        float4 f0 = *reinterpret_cast<const float4*>(sp);
        float4 f1 = *reinterpret_cast<const float4*>(sp + 4);
        Bh[lt].u[0] = pkh(f0.x, f0.y);
        Bh[lt].u[1] = pkh(f0.z, f0.w);
        Bh[lt].u[2] = pkh(f1.x, f1.y);
        Bh[lt].u[3] = pkh(f1.z, f1.w);
    }

    // --- per-shapelet sum of squares (fp32) ---
    if (tid < NL) {
        const float* sp = shapelets + tid * KLEN;
        float s = 0.0f;
        #pragma unroll
        for (int k = 0; k < KLEN; ++k) s = fmaf(sp[k], sp[k], s);
        lds_ssq[tid] = s;
    }
    __syncthreads();

    // --- pass 2 (both rows): win_sq from partials + f16 sliding corrections ---
    #pragma unroll
    for (int r = 0; r < ROWS; ++r) {
        float s[8];
        #pragma unroll
        for (int j = 0; j < 8; ++j) s[j] = lds_s4[r][tid + j];
        float w0 = ((s[0] + s[1]) + (s[2] + s[3])) + ((s[4] + s[5]) + (s[6] + s[7]));
        uint32_t a0 = lds_pkE[r][2 * tid];
        uint32_t a1 = lds_pkE[r][2 * tid + 1];
        uint32_t c0 = lds_pkE[r][2 * (tid + 8)];
        uint32_t c1 = lds_pkE[r][2 * (tid + 8) + 1];
        float x0 = lo16f(a0), x1 = hi16f(a0), x2 = lo16f(a1);
        float x32 = lo16f(c0), x33 = hi16f(c0), x34 = lo16f(c1);
        float w1 = fmaf(x32, x32, fmaf(-x0, x0, w0));
        float w2 = fmaf(x33, x33, fmaf(-x1, x1, w1));
        float w3 = fmaf(x34, x34, fmaf(-x2, x2, w2));
        const int p0 = 4 * tid;
        float4 wv;
        wv.x = (p0 + 0 < NS) ? -0.5f * w0 : -1.0e30f;
        wv.y = (p0 + 1 < NS) ? -0.5f * w1 : -1.0e30f;
        wv.z = (p0 + 2 < NS) ? -0.5f * w2 : -1.0e30f;
        wv.w = (p0 + 3 < NS) ? -0.5f * w3 : -1.0e30f;
        reinterpret_cast<float4*>(lds_nwin[r])[tid] = wv;
    }
    __syncthreads();

    // --- main loops: r7's EXACT loop shape per row (unroll 2, loads at head) ---
    const int par = col & 1;
    const int abase = ((col - par) >> 1) + kg * 4;
    float* pm = &lds_s4[0][0];   // alias (s4 dead after pass2 barrier); 512 floats

    #pragma unroll 1
    for (int r = 0; r < ROWS; ++r) {
        const uint32_t* apk = (par ? lds_pkO[r] : lds_pkE[r]) + abase;
        const float*    nw  = lds_nwin[r];

        float rmax[4][4];
        #pragma unroll
        for (int lt = 0; lt < 4; ++lt)
            #pragma unroll
            for (int e = 0; e < 4; ++e) rmax[lt][e] = -3.0e38f;

        #pragma unroll 2
        for (int i = 0; i < 8; ++i) {
            const int s0 = 32 * wave + 128 * i;
            const uint32_t* ap = apk + (s0 >> 1);
            fragh Aa, Ab;
            #pragma unroll
            for (int j = 0; j < 4; ++j) Aa.u[j] = ap[j];
            #pragma unroll
            for (int j = 0; j < 4; ++j) Ab.u[j] = ap[8 + j];
            const f32x4 ia = *reinterpret_cast<const f32x4*>(nw + s0 + kg * 4);
            const f32x4 ib = *reinterpret_cast<const f32x4*>(nw + s0 + 16 + kg * 4);

            #pragma unroll
            for (int lt = 0; lt < 4; ++lt) {
                f32x4 aa = __builtin_amdgcn_mfma_f32_16x16x32_f16(Aa.v, Bh[lt].v, ia, 0, 0, 0);
                f32x4 ab = __builtin_amdgcn_mfma_f32_16x16x32_f16(Ab.v, Bh[lt].v, ib, 0, 0, 0);
                #pragma unroll
                for (int e = 0; e < 4; ++e)
                    rmax[lt][e] = fmaxf(fmaxf(aa[e], ab[e]), rmax[lt][e]);  // v_max3_f32
            }
        }

        // reduce: within-lane, cross-kg (same col); stash per-wave partials
        #pragma unroll
        for (int lt = 0; lt < 4; ++lt) {
            float v = fmaxf(fmaxf(rmax[lt][0], rmax[lt][1]),
                            fmaxf(rmax[lt][2], rmax[lt][3]));
            v = fmaxf(v, __shfl_xor(v, 16, 64));
            v = fmaxf(v, __shfl_xor(v, 32, 64));
            if (kg == 0) pm[r * 256 + wave * 64 + lt * 16 + col] = v;
        }
    }
    __syncthreads();

    // --- epilogue: wave r handles row b0+r ---
    if (wave < ROWS) {
        const int r = wave;
        float m = fmaxf(fmaxf(pm[r * 256 + 0 * 64 + lane], pm[r * 256 + 1 * 64 + lane]),
                        fmaxf(pm[r * 256 + 2 * 64 + lane], pm[r * 256 + 3 * 64 + lane]));
        float f = (lds_ssq[lane] - 2.0f * m) * (1.0f / (float)KLEN);  // min dist

        float p0v = f * fc_w[lane];
        float p1v = f * fc_w[NL + lane];
        #pragma unroll
        for (int off = 32; off >= 1; off >>= 1) {
            p0v += __shfl_xor(p0v, off, 64);
            p1v += __shfl_xor(p1v, off, 64);
        }
        if (lane == 0) {
            out[(size_t)(b0 + r) * 2 + 0] = p0v + fc_b[0];
            out[(size_t)(b0 + r) * 2 + 1] = p1v + fc_b[1];
        }
    }
}

extern "C" void kernel_launch(void* const* d_in, const int* in_sizes, int n_in,
                              void* d_out, int out_size, void* d_ws, size_t ws_size,
                              hipStream_t stream) {
    const float* ts        = (const float*)d_in[0];
    const float* shapelets = (const float*)d_in[1];
    const float* fc_w      = (const float*)d_in[2];
    const float* fc_b      = (const float*)d_in[3];
    float* out = (float*)d_out;

    shapelet_r9<<<NB / ROWS, 256, 0, stream>>>(ts, shapelets, fc_w, fc_b, out);
}

// Round 10
// 28.760 us; speedup vs baseline: 8.0790x; 1.0299x over previous
//
#include <hip/hip_runtime.h>
#include <stdint.h>

#define NB 4096
#define QLEN 1024
#define NL 64
#define KLEN 32
#define NS (QLEN - KLEN + 1)   // 993

typedef __attribute__((ext_vector_type(8))) _Float16 half8;
typedef __attribute__((ext_vector_type(4))) float f32x4;

union fragh { uint32_t u[4]; half8 v; };

static __device__ __forceinline__ uint32_t pkh(float a, float b) {
    return __builtin_bit_cast(uint32_t, __builtin_amdgcn_cvt_pkrtz(a, b)); // v_cvt_pkrtz_f16_f32
}
static __device__ __forceinline__ float lo16f(uint32_t w) {
    return (float)__builtin_bit_cast(_Float16, (unsigned short)(w & 0xFFFFu));
}
static __device__ __forceinline__ float hi16f(uint32_t w) {
    return (float)__builtin_bit_cast(_Float16, (unsigned short)(w >> 16));
}
static __device__ __forceinline__ uint32_t pkh_rne(float a, float b) {  // RNE f16 pair
    unsigned short ha = __builtin_bit_cast(unsigned short, (_Float16)a);
    unsigned short hb = __builtin_bit_cast(unsigned short, (_Float16)b);
    return (uint32_t)ha | ((uint32_t)hb << 16);
}

__global__ __launch_bounds__(256, 6) void shapelet_r10(
    const float* __restrict__ ts,        // [B, Q]
    const float* __restrict__ shapelets, // [L, K]
    const float* __restrict__ fc_w,      // [2, L]
    const float* __restrict__ fc_b,      // [2]
    float* __restrict__ out)             // [B, 2]
{
    __shared__ __align__(16) uint32_t lds_pkE[544];   // f16(x[2i]) | f16(x[2i+1])<<16
    __shared__ __align__(16) uint32_t lds_pkO[544];   // f16(x[2i+1]) | f16(x[2i+2])<<16
    __shared__ __align__(16) uint32_t lds_nwh[512];   // -0.5*win as f16 pairs, MFMA-frag layout
    __shared__ __align__(16) float    lds_s4[264];    // per-thread 4-square partials
    __shared__ float lds_ssq[NL];
    __shared__ float lds_pm[4][NL];

    const int tid  = threadIdx.x;
    const int b    = blockIdx.x;
    const int lane = tid & 63;
    const int wave = tid >> 6;
    const int col  = lane & 15;
    const int kg   = lane >> 4;

    // --- pass 1: own float4 + next dword from global; pack f16; s4 partial ---
    float x0, x1, x2;
    {
        float4 v = reinterpret_cast<const float4*>(ts + (size_t)b * QLEN)[tid];
        x0 = v.x; x1 = v.y; x2 = v.z;
        float x3 = v.w;
        float x4g = (tid < 255) ? ts[(size_t)b * QLEN + 4 * tid + 4] : 0.0f;
        uint2 pe = { pkh(x0, x1), pkh(x2, x3) };
        uint2 po = { pkh(x1, x2), pkh(x3, x4g) };
        reinterpret_cast<uint2*>(lds_pkE)[tid] = pe;
        reinterpret_cast<uint2*>(lds_pkO)[tid] = po;
        lds_s4[tid] = fmaf(x0, x0, fmaf(x1, x1, fmaf(x2, x2, x3 * x3)));
    }
    if (tid < 32) { lds_pkE[512 + tid] = 0u; lds_pkO[512 + tid] = 0u; }
    if (tid < 8)  lds_s4[256 + tid] = 0.0f;

    // --- B fragments: fp16 RTZ, all 4 l-tiles (16 VGPR) ---
    fragh Bh[4];
    #pragma unroll
    for (int lt = 0; lt < 4; ++lt) {
        const float* sp = shapelets + (lt * 16 + col) * KLEN + kg * 8;
        float4 f0 = *reinterpret_cast<const float4*>(sp);
        float4 f1 = *reinterpret_cast<const float4*>(sp + 4);
        Bh[lt].u[0] = pkh(f0.x, f0.y);
        Bh[lt].u[1] = pkh(f0.z, f0.w);
        Bh[lt].u[2] = pkh(f1.x, f1.y);
        Bh[lt].u[3] = pkh(f1.z, f1.w);
    }

    // --- per-shapelet sum of squares (fp32, global reads, L2-cached) ---
    if (tid < NL) {
        const float* sp = shapelets + tid * KLEN;
        float s = 0.0f;
        #pragma unroll
        for (int k = 0; k < KLEN; ++k) s = fmaf(sp[k], sp[k], s);
        lds_ssq[tid] = s;
    }
    __syncthreads();

    // --- pass 2: win_sq from s4 partials + f16 sliding corrections;
    //     store -0.5*win as f16 pairs in the per-(tilepair,kg) fragment layout ---
    {
        float s[8];
        #pragma unroll
        for (int j = 0; j < 8; ++j) s[j] = lds_s4[tid + j];
        float w0 = ((s[0] + s[1]) + (s[2] + s[3])) + ((s[4] + s[5]) + (s[6] + s[7]));
        uint32_t cw0 = lds_pkE[2 * (tid + 8)];
        uint32_t cw1 = lds_pkE[2 * (tid + 8) + 1];
        float x32 = lo16f(cw0), x33 = hi16f(cw0), x34 = lo16f(cw1);
        float w1 = fmaf(x32, x32, fmaf(-x0, x0, w0));
        float w2 = fmaf(x33, x33, fmaf(-x1, x1, w1));
        float w3 = fmaf(x34, x34, fmaf(-x2, x2, w2));
        const int p0 = 4 * tid;
        float c0 = (p0 + 0 < NS) ? -0.5f * w0 : -60000.0f;
        float c1 = (p0 + 1 < NS) ? -0.5f * w1 : -60000.0f;
        float c2 = (p0 + 2 < NS) ? -0.5f * w2 : -60000.0f;
        float c3 = (p0 + 3 < NS) ? -0.5f * w3 : -60000.0f;
        // word index: W = 16*t + 4*kg' + 2*(half) with t=p>>5, kg'=(p&15)>>2, half=(p&31)>>4
        const int q = p0 & 31;
        const int W = ((p0 >> 5) << 4) + (((q & 15) >> 2) << 2) + ((q >> 4) << 1);
        uint2 hw = { pkh_rne(c0, c1), pkh_rne(c2, c3) };
        *reinterpret_cast<uint2*>(&lds_nwh[W]) = hw;
    }
    __syncthreads();

    // --- main loop: r7's exact loop shape; nwin now ONE b128 read + 8 cvt ---
    float rmax[4][4];
    #pragma unroll
    for (int lt = 0; lt < 4; ++lt)
        #pragma unroll
        for (int e = 0; e < 4; ++e) rmax[lt][e] = -3.0e38f;

    const int par = col & 1;
    const uint32_t* apk = par ? lds_pkO : lds_pkE;
    const int abase = ((col - par) >> 1) + kg * 4;
    const int nwb = 4 * kg;

    #pragma unroll 2
    for (int i = 0; i < 8; ++i) {
        const int s0 = 32 * wave + 128 * i;
        const int tp = wave + 4 * i;                  // tile-pair index
        const uint32_t* ap = apk + (s0 >> 1) + abase;
        fragh Aa, Ab;
        #pragma unroll
        for (int j = 0; j < 4; ++j) Aa.u[j] = ap[j];
        #pragma unroll
        for (int j = 0; j < 4; ++j) Ab.u[j] = ap[8 + j];

        uint4 nw = *reinterpret_cast<const uint4*>(&lds_nwh[16 * tp + nwb]);
        f32x4 ia, ib;
        ia[0] = lo16f(nw.x); ia[1] = hi16f(nw.x);
        ia[2] = lo16f(nw.y); ia[3] = hi16f(nw.y);
        ib[0] = lo16f(nw.z); ib[1] = hi16f(nw.z);
        ib[2] = lo16f(nw.w); ib[3] = hi16f(nw.w);

        #pragma unroll
        for (int lt = 0; lt < 4; ++lt) {
            f32x4 aa = __builtin_amdgcn_mfma_f32_16x16x32_f16(Aa.v, Bh[lt].v, ia, 0, 0, 0);
            f32x4 ab = __builtin_amdgcn_mfma_f32_16x16x32_f16(Ab.v, Bh[lt].v, ib, 0, 0, 0);
            #pragma unroll
            for (int e = 0; e < 4; ++e)
                rmax[lt][e] = fmaxf(fmaxf(aa[e], ab[e]), rmax[lt][e]);  // v_max3_f32
        }
    }

    // --- reduce: within-lane, cross-kg (same col), cross-wave ---
    #pragma unroll
    for (int lt = 0; lt < 4; ++lt) {
        float v = fmaxf(fmaxf(rmax[lt][0], rmax[lt][1]),
                        fmaxf(rmax[lt][2], rmax[lt][3]));
        v = fmaxf(v, __shfl_xor(v, 16, 64));
        v = fmaxf(v, __shfl_xor(v, 32, 64));
        if (kg == 0) lds_pm[wave][lt * 16 + col] = v;
    }
    __syncthreads();

    if (wave == 0) {
        float m = fmaxf(fmaxf(lds_pm[0][lane], lds_pm[1][lane]),
                        fmaxf(lds_pm[2][lane], lds_pm[3][lane]));
        float f = (lds_ssq[lane] - 2.0f * m) * (1.0f / (float)KLEN);  // min dist

        float p0v = f * fc_w[lane];
        float p1v = f * fc_w[NL + lane];
        #pragma unroll
        for (int off = 32; off >= 1; off >>= 1) {
            p0v += __shfl_xor(p0v, off, 64);
            p1v += __shfl_xor(p1v, off, 64);
        }
        if (lane == 0) {
            out[(size_t)b * 2 + 0] = p0v + fc_b[0];
            out[(size_t)b * 2 + 1] = p1v + fc_b[1];
        }
    }
}

extern "C" void kernel_launch(void* const* d_in, const int* in_sizes, int n_in,
                              void* d_out, int out_size, void* d_ws, size_t ws_size,
                              hipStream_t stream) {
    const float* ts        = (const float*)d_in[0];
    const float* shapelets = (const float*)d_in[1];
    const float* fc_w      = (const float*)d_in[2];
    const float* fc_b      = (const float*)d_in[3];
    float* out = (float*)d_out;

    shapelet_r10<<<NB, 256, 0, stream>>>(ts, shapelets, fc_w, fc_b, out);
}